// Round 3
// baseline (492.650 us; speedup 1.0000x reference)
//
#include <hip/hip_runtime.h>

#define B_  32
#define C1  1024
#define C2  256
#define T_  2048
#define EPSF 1e-5f
#define BPITCH 40   // sB row pitch in halfwords (80 B = 20 dwords; with k-slot XOR swizzle)

typedef __attribute__((ext_vector_type(8))) short bf16x8;
typedef __attribute__((ext_vector_type(4))) float f32x4;

static __device__ __forceinline__ unsigned short f2bf(float f) {
    union { float f; unsigned u; } v; v.f = f;
    unsigned r = v.u + 0x7fffu + ((v.u >> 16) & 1u);   // RNE
    return (unsigned short)(r >> 16);
}
// async global->LDS, 16 B per lane; lds dest = wave-uniform base + lane*16
static __device__ __forceinline__ void g2l16(const void* g, void* l) {
    __builtin_amdgcn_global_load_lds(
        (const __attribute__((address_space(1))) unsigned int*)g,
        (__attribute__((address_space(3))) unsigned int*)l, 16, 0, 0);
}
// row-dependent k-group swizzle for sB: slot = kk ^ (swz(t)<<3)
// swz(t) chosen so write banks = 16(tc&1) + 4(w^swz) + p -> all 32 banks (conflict-free)
static __device__ __forceinline__ int bswz(int t) {
    return ((t >> 2) & 3) ^ ((t >> 4) & 1);
}

// ---- K1: pure-read per-(b,c) partial stats. No LDS, no barriers.
__global__ __launch_bounds__(256) void k_stats(const float* __restrict__ x,
        float* __restrict__ psum, float* __restrict__ psq) {
    int ct = blockIdx.x, b = blockIdx.y, tid = threadIdx.x;
    int c0 = ct * 64;
    int cl = tid >> 2, t4 = tid & 3;
    const float* xrow = x + (size_t)b * C1 * T_ + (size_t)(c0 + cl) * T_ + t4 * 4;
    float s = 0.f, sq = 0.f;
    #pragma unroll 4
    for (int t0 = 0; t0 < T_; t0 += 16) {
        float4 v = *(const float4*)(xrow + t0);
        s  += v.x + v.y + v.z + v.w;
        sq += v.x * v.x + v.y * v.y + v.z * v.z + v.w * v.w;
    }
    s  += __shfl_xor(s, 1);  s  += __shfl_xor(s, 2);   // reduce over the 4-lane quad
    sq += __shfl_xor(sq, 1); sq += __shfl_xor(sq, 2);
    if (t4 == 0) {
        psum[(size_t)b * C1 + c0 + cl] = s;
        psq [(size_t)b * C1 + c0 + cl] = sq;
    }
}

// ---- K2: fused bnstat1+fold1. Block o; thread owns channels c..c+3 for BOTH the
// (redundant, L2-hot) stat reduction and the weight fold — no exchange needed.
// Also initializes b2e = b2 (needed by k_bnfold2's atomics).
__global__ __launch_bounds__(256) void k_bnfold1(const float* __restrict__ w1,
        const float* __restrict__ b1, const float* __restrict__ g1,
        const float* __restrict__ bb1, const float* __restrict__ psum,
        const float* __restrict__ psq, unsigned short* __restrict__ w1e,
        float* __restrict__ b1e, const float* __restrict__ b2, float* __restrict__ b2e) {
    int o = blockIdx.x, tid = threadIdx.x;
    int c = tid * 4;
    float4 s = {0,0,0,0}, sq = {0,0,0,0};
    for (int b = 0; b < B_; ++b) {
        float4 a = *(const float4*)(psum + (size_t)b * C1 + c);
        float4 q = *(const float4*)(psq  + (size_t)b * C1 + c);
        s.x += a.x; s.y += a.y; s.z += a.z; s.w += a.w;
        sq.x += q.x; sq.y += q.y; sq.z += q.z; sq.w += q.w;
    }
    const float n = (float)(B_ * T_);
    float4 gg = *(const float4*)(g1 + c);
    float4 bv = *(const float4*)(bb1 + c);
    float m0 = s.x / n, m1 = s.y / n, m2 = s.z / n, m3 = s.w / n;
    float sc0 = gg.x * rsqrtf(sq.x / n - m0 * m0 + EPSF);
    float sc1 = gg.y * rsqrtf(sq.y / n - m1 * m1 + EPSF);
    float sc2 = gg.z * rsqrtf(sq.z / n - m2 * m2 + EPSF);
    float sc3 = gg.w * rsqrtf(sq.w / n - m3 * m3 + EPSF);
    float sh0 = bv.x - m0 * sc0, sh1 = bv.y - m1 * sc1;
    float sh2 = bv.z - m2 * sc2, sh3 = bv.w - m3 * sc3;
    float4 w = ((const float4*)(w1 + (size_t)o * C1))[tid];
    float p = w.x * sh0 + w.y * sh1 + w.z * sh2 + w.w * sh3;
    uint2 pk;
    pk.x = (unsigned)f2bf(w.x * sc0) | ((unsigned)f2bf(w.y * sc1) << 16);
    pk.y = (unsigned)f2bf(w.z * sc2) | ((unsigned)f2bf(w.w * sc3) << 16);
    *((uint2*)(w1e + (size_t)o * C1 + c)) = pk;
    int wave = tid >> 6, lane = tid & 63;
    for (int m = 1; m < 64; m <<= 1) p += __shfl_xor(p, m);
    __shared__ float rs[4];
    if (lane == 0) rs[wave] = p;
    __syncthreads();
    if (tid == 0) {
        b1e[o] = b1[o] + rs[0] + rs[1] + rs[2] + rs[3];
        if (o < 64) b2e[o] = b2[o];               // init for bnfold2 atomics
    }
}

// ---- K3: GEMM1 256(o)x128(t), K=1024, BK=32, double-buffered.
// B staged from x f32 -> regs -> f2bf -> swizzled ds_write (conflict-free).
__global__ __launch_bounds__(256, 2) void k_gemm1(const float* __restrict__ x,
        const unsigned short* __restrict__ w1e, const float* __restrict__ b1e,
        unsigned short* __restrict__ hT, float* __restrict__ p2s, float* __restrict__ p2q) {
    __shared__ alignas(16) unsigned short sA[2][256 * 32];      // 2 x 16 KiB  w1e tile [o][k]
    __shared__ alignas(16) unsigned short sB[2][128 * BPITCH];  // 2 x 10 KiB  x tile [t][k-swz]
    int bn = blockIdx.x, b = blockIdx.y;
    int tid = threadIdx.x;
    int wave = tid >> 6, lane = tid & 63;
    int wm = wave >> 1, wn = wave & 1;        // wave: 128(o) x 64(t)
    int l15 = lane & 15, q = lane >> 4;
    f32x4 acc[8][4] = {};

    // B staging geometry: thread -> (kk = tid>>3 in 0..31, tc = tid&7)
    int kk = tid >> 3, tc = tid & 7;
    const float* xbase = x + (size_t)b * C1 * T_ + (size_t)kk * T_ + (size_t)bn * 128 + tc * 4;

    auto stageA = [&](int buf, int k0) {
        #pragma unroll
        for (int i = 0; i < 4; ++i) {         // 16 segments of 1 KiB
            int idx = (wave * 4 + i) * 64 + lane;
            int row = idx >> 2, cq = idx & 3;
            g2l16(w1e + (size_t)row * C1 + k0 + cq * 8, &sA[buf][(wave * 4 + i) * 512]);
        }
    };
    float4 rB[4];
    auto loadB = [&](int k0) {
        #pragma unroll
        for (int j = 0; j < 4; ++j)
            rB[j] = *(const float4*)(xbase + (size_t)k0 * T_ + j * 32);
    };
    auto writeB = [&](int buf) {
        #pragma unroll
        for (int j = 0; j < 4; ++j) {
            int t = tc * 4 + j * 32;
            int slot = kk ^ (bswz(t) << 3);   // t..t+3 share t>>2 -> same swizzle
            unsigned short* p = &sB[buf][t * BPITCH + slot];
            p[0 * BPITCH] = f2bf(rB[j].x);
            p[1 * BPITCH] = f2bf(rB[j].y);
            p[2 * BPITCH] = f2bf(rB[j].z);
            p[3 * BPITCH] = f2bf(rB[j].w);
        }
    };

    loadB(0);
    stageA(0, 0);
    writeB(0);
    __syncthreads();                           // sB0 visible + sA0 g2l16 drained
    int cur = 0;
    for (int kt = 0; kt < 32; ++kt) {
        int nxt = cur ^ 1;
        if (kt < 31) {
            loadB((kt + 1) * 32);              // issue early (oldest in vmcnt queue)
            stageA(nxt, (kt + 1) * 32);
        }
        bf16x8 bfr[4];
        #pragma unroll
        for (int ni = 0; ni < 4; ++ni) {
            int t = wn * 64 + ni * 16 + l15;
            bfr[ni] = *((const bf16x8*)&sB[cur][t * BPITCH + ((q ^ bswz(t)) << 3)]);
        }
        #pragma unroll
        for (int mi = 0; mi < 8; ++mi) {
            bf16x8 af = *((const bf16x8*)&sA[cur][(wm * 128 + mi * 16 + l15) * 32 + q * 8]);
            #pragma unroll
            for (int ni = 0; ni < 4; ++ni)
                acc[mi][ni] = __builtin_amdgcn_mfma_f32_16x16x32_bf16(af, bfr[ni], acc[mi][ni], 0, 0, 0);
        }
        if (kt < 31) writeB(nxt);              // vmcnt(4): rB arrived, A-g2l16 stays in flight
        __syncthreads();
        cur = nxt;
    }
    // epilogue. C/D: col(t)=l15, row(o)=q*4+reg
    int obase = wm * 128;
    int tbase = bn * 128 + wn * 64;
    int prow = (b * 16 + bn) * 2 + wn;        // 1024 partial rows
    #pragma unroll
    for (int mi = 0; mi < 8; ++mi) {
        int og = obase + mi * 16 + q * 4;
        float4 bias = *(const float4*)&b1e[og];
        float s0 = 0, s1 = 0, s2 = 0, s3 = 0, q0 = 0, q1 = 0, q2 = 0, q3 = 0;
        #pragma unroll
        for (int ni = 0; ni < 4; ++ni) {
            int t = tbase + ni * 16 + l15;
            float v0 = fmaxf(acc[mi][ni][0] + bias.x, 0.f);
            float v1 = fmaxf(acc[mi][ni][1] + bias.y, 0.f);
            float v2 = fmaxf(acc[mi][ni][2] + bias.z, 0.f);
            float v3 = fmaxf(acc[mi][ni][3] + bias.w, 0.f);
            s0 += v0; q0 += v0 * v0;  s1 += v1; q1 += v1 * v1;
            s2 += v2; q2 += v2 * v2;  s3 += v3; q3 += v3 * v3;
            uint2 pk;
            pk.x = (unsigned)f2bf(v0) | ((unsigned)f2bf(v1) << 16);
            pk.y = (unsigned)f2bf(v2) | ((unsigned)f2bf(v3) << 16);
            *(uint2*)&hT[((size_t)b * T_ + t) * C2 + og] = pk;
        }
        #pragma unroll
        for (int m = 1; m <= 8; m <<= 1) {    // butterfly over l15 (16-lane groups)
            s0 += __shfl_xor(s0, m); s1 += __shfl_xor(s1, m);
            s2 += __shfl_xor(s2, m); s3 += __shfl_xor(s3, m);
            q0 += __shfl_xor(q0, m); q1 += __shfl_xor(q1, m);
            q2 += __shfl_xor(q2, m); q3 += __shfl_xor(q3, m);
        }
        if (l15 == 0) {                        // transposed partials: [c][row]
            p2s[(size_t)(og + 0) * 1024 + prow] = s0;
            p2s[(size_t)(og + 1) * 1024 + prow] = s1;
            p2s[(size_t)(og + 2) * 1024 + prow] = s2;
            p2s[(size_t)(og + 3) * 1024 + prow] = s3;
            p2q[(size_t)(og + 0) * 1024 + prow] = q0;
            p2q[(size_t)(og + 1) * 1024 + prow] = q1;
            p2q[(size_t)(og + 2) * 1024 + prow] = q2;
            p2q[(size_t)(og + 3) * 1024 + prow] = q3;
        }
    }
}

// ---- K4: fused bnstat2+fold2. Block c: coalesced row-reduce of p2s/p2q[c][*],
// then threads 0..63 fold w2[o][c] and atomically accumulate b2e[o].
__global__ __launch_bounds__(256) void k_bnfold2(const float* __restrict__ p2s,
        const float* __restrict__ p2q, const float* __restrict__ g2,
        const float* __restrict__ bb2, const float* __restrict__ w2,
        unsigned short* __restrict__ w2e, float* __restrict__ b2e) {
    int c = blockIdx.x, tid = threadIdx.x;
    float4 a  = *(const float4*)(p2s + (size_t)c * 1024 + tid * 4);
    float4 qv = *(const float4*)(p2q + (size_t)c * 1024 + tid * 4);
    float s = a.x + a.y + a.z + a.w;
    float q = qv.x + qv.y + qv.z + qv.w;
    for (int m = 1; m < 64; m <<= 1) { s += __shfl_xor(s, m); q += __shfl_xor(q, m); }
    __shared__ float rs[4], rq[4], bc[2];
    int wave = tid >> 6, lane = tid & 63;
    if (lane == 0) { rs[wave] = s; rq[wave] = q; }
    __syncthreads();
    if (tid == 0) {
        s = rs[0] + rs[1] + rs[2] + rs[3];
        q = rq[0] + rq[1] + rq[2] + rq[3];
        const float n = (float)(B_ * T_);
        float m0 = s / n;
        float sc = g2[c] * rsqrtf(q / n - m0 * m0 + EPSF);
        bc[0] = sc;
        bc[1] = bb2[c] - m0 * sc;
    }
    __syncthreads();
    if (tid < 64) {                            // tid == o
        float wv = w2[(size_t)tid * C2 + c];
        w2e[(size_t)tid * C2 + c] = f2bf(wv * bc[0]);
        atomicAdd(&b2e[tid], wv * bc[1]);
    }
}

// ---- K5: GEMM2 (double-buffered): out = w2e @ hT + b2e, split mu/logvar.
__global__ __launch_bounds__(256) void k_gemm2(const unsigned short* __restrict__ hT,
        const unsigned short* __restrict__ w2e, const float* __restrict__ b2e,
        float* __restrict__ out) {
    __shared__ alignas(16) unsigned short sA[2][64 * 32];    // 2 x 4 KiB
    __shared__ alignas(16) unsigned short sB[2][128 * 32];   // 2 x 8 KiB
    int bn = blockIdx.x, b = blockIdx.y;
    int tid = threadIdx.x;
    int wave = tid >> 6, lane = tid & 63;
    int l15 = lane & 15, q = lane >> 4;
    f32x4 acc[4][2] = {};
    const unsigned short* hblk = hT + ((size_t)b * T_ + (size_t)bn * 128) * C2;

    auto stage = [&](int buf, int k0) {
        {                                      // A: 4 segments, one per wave
            int idx = wave * 64 + lane;
            int row = idx >> 2, cq = idx & 3;
            g2l16(w2e + (size_t)row * C2 + k0 + cq * 8, &sA[buf][wave * 512]);
        }
        #pragma unroll
        for (int i = 0; i < 2; ++i) {          // B: 8 segments
            int idx = (wave * 2 + i) * 64 + lane;
            int row = idx >> 2, cq = idx & 3;
            g2l16(hblk + (size_t)row * C2 + k0 + cq * 8, &sB[buf][(wave * 2 + i) * 512]);
        }
    };

    stage(0, 0);
    __syncthreads();
    int cur = 0;
    for (int kt = 0; kt < 8; ++kt) {
        if (kt < 7) stage(cur ^ 1, (kt + 1) * 32);
        bf16x8 af[4], bfr[2];
        #pragma unroll
        for (int mi = 0; mi < 4; ++mi)
            af[mi] = *((const bf16x8*)&sA[cur][(mi * 16 + l15) * 32 + q * 8]);
        #pragma unroll
        for (int ni = 0; ni < 2; ++ni)
            bfr[ni] = *((const bf16x8*)&sB[cur][(wave * 32 + ni * 16 + l15) * 32 + q * 8]);
        #pragma unroll
        for (int mi = 0; mi < 4; ++mi)
            #pragma unroll
            for (int ni = 0; ni < 2; ++ni)
                acc[mi][ni] = __builtin_amdgcn_mfma_f32_16x16x32_bf16(af[mi], bfr[ni], acc[mi][ni], 0, 0, 0);
        __syncthreads();
        cur ^= 1;
    }
    int tbase = bn * 128 + wave * 32;
    #pragma unroll
    for (int mi = 0; mi < 4; ++mi) {
        #pragma unroll
        for (int reg = 0; reg < 4; ++reg) {
            int o = mi * 16 + q * 4 + reg;
            float bias = b2e[o];
            size_t base = (o < 32)
                ? ((size_t)b * 32 * T_ + (size_t)o * T_)
                : (2097152u + (size_t)b * 32 * T_ + (size_t)(o - 32) * T_);
            #pragma unroll
            for (int ni = 0; ni < 2; ++ni) {
                int t = tbase + ni * 16 + l15;
                out[base + t] = acc[mi][ni][reg] + bias;
            }
        }
    }
}

extern "C" void kernel_launch(void* const* d_in, const int* in_sizes, int n_in,
                              void* d_out, int out_size, void* d_ws, size_t ws_size,
                              hipStream_t stream) {
    const float* x   = (const float*)d_in[0];
    const float* g1  = (const float*)d_in[1];
    const float* bb1 = (const float*)d_in[2];
    const float* w1  = (const float*)d_in[3];
    const float* b1  = (const float*)d_in[4];
    const float* g2  = (const float*)d_in[5];
    const float* bb2 = (const float*)d_in[6];
    const float* w2  = (const float*)d_in[7];
    const float* b2  = (const float*)d_in[8];
    float* out = (float*)d_out;

    char* ws = (char*)d_ws;
    float* b1e  = (float*)(ws + 0);                       //   1 KiB (pad 4K)
    float* b2e  = (float*)(ws + 4096);                    // 256 B  (pad 4K)
    float* psum = (float*)(ws + 8192);                    // 128 KiB [32][1024]
    float* psq  = (float*)(ws + 139264);                  // 128 KiB
    float* p2s  = (float*)(ws + 270336);                  //   1 MiB [256][1024] (transposed)
    float* p2q  = (float*)(ws + 1318912);                 //   1 MiB
    unsigned short* w1e = (unsigned short*)(ws + 2367488);    // 512 KiB
    unsigned short* w2e = (unsigned short*)(ws + 2891776);    //  32 KiB
    unsigned short* hT  = (unsigned short*)(ws + 2924544);    //  32 MiB [b][t][c2]

    k_stats  <<<dim3(16, 32), dim3(256), 0, stream>>>(x, psum, psq);
    k_bnfold1<<<dim3(256),    dim3(256), 0, stream>>>(w1, b1, g1, bb1, psum, psq, w1e, b1e, b2, b2e);
    k_gemm1  <<<dim3(16, 32), dim3(256), 0, stream>>>(x, w1e, b1e, hT, p2s, p2q);
    k_bnfold2<<<dim3(256),    dim3(256), 0, stream>>>(p2s, p2q, g2, bb2, w2, w2e, b2e);
    k_gemm2  <<<dim3(16, 32), dim3(256), 0, stream>>>(hT, w2e, b2e, out);
}

// Round 5
// 483.214 us; speedup vs baseline: 1.0195x; 1.0195x over previous
//
#include <hip/hip_runtime.h>
#include <hip/hip_cooperative_groups.h>

namespace cg = cooperative_groups;

#define B_  32
#define C1  1024
#define C2  256
#define T_  2048
#define EPSF 1e-5f
#define BPITCH 40   // gemm1 sB row pitch in halfwords (80 B)

typedef __attribute__((ext_vector_type(8))) short bf16x8;
typedef __attribute__((ext_vector_type(4))) float f32x4;

static __device__ __forceinline__ unsigned short f2bf(float f) {
    union { float f; unsigned u; } v; v.f = f;
    unsigned r = v.u + 0x7fffu + ((v.u >> 16) & 1u);   // RNE
    return (unsigned short)(r >> 16);
}
// async global->LDS, 16 B per lane; lds dest = wave-uniform base + lane*16
static __device__ __forceinline__ void g2l16(const void* g, void* l) {
    __builtin_amdgcn_global_load_lds(
        (const __attribute__((address_space(1))) unsigned int*)g,
        (__attribute__((address_space(3))) unsigned int*)l, 16, 0, 0);
}

// ===================== Cooperative mega-kernel (R4-audited bodies) =====================
__global__ __launch_bounds__(256, 2) void k_mega(
        const float* __restrict__ x,
        const float* __restrict__ g1, const float* __restrict__ bb1,
        const float* __restrict__ w1, const float* __restrict__ b1,
        const float* __restrict__ g2, const float* __restrict__ bb2,
        const float* __restrict__ w2, const float* __restrict__ b2,
        float* __restrict__ out,
        float* __restrict__ psum, float* __restrict__ psq,
        float* __restrict__ p2s, float* __restrict__ p2q,
        unsigned short* __restrict__ w1e, unsigned short* __restrict__ w2e,
        float* __restrict__ b1e, float* __restrict__ b2e,
        float* __restrict__ sc1v, float* __restrict__ sh1v,
        float* __restrict__ sc2v, float* __restrict__ sh2v,
        unsigned short* __restrict__ hT) {
    __shared__ alignas(16) unsigned char smem[53248];   // 52 KiB (gemm1 union max)
    cg::grid_group grid = cg::this_grid();
    int bid = blockIdx.x, tid = threadIdx.x;
    int wave = tid >> 6, lane = tid & 63;
    const float n = (float)(B_ * T_);

    // ---- Phase 1: per-(b,c) partial stats (pure read)
    {
        int ct = bid & 15, b = bid >> 4;
        int c0 = ct * 64;
        int cl = tid >> 2, t4 = tid & 3;
        const float* xrow = x + (size_t)b * C1 * T_ + (size_t)(c0 + cl) * T_ + t4 * 4;
        float s = 0.f, sq = 0.f;
        #pragma unroll 4
        for (int t0 = 0; t0 < T_; t0 += 16) {
            float4 v = *(const float4*)(xrow + t0);
            s  += v.x + v.y + v.z + v.w;
            sq += v.x * v.x + v.y * v.y + v.z * v.z + v.w * v.w;
        }
        s  += __shfl_xor(s, 1);  s  += __shfl_xor(s, 2);
        sq += __shfl_xor(sq, 1); sq += __shfl_xor(sq, 2);
        if (t4 == 0) {
            psum[(size_t)b * C1 + c0 + cl] = s;
            psq [(size_t)b * C1 + c0 + cl] = sq;
        }
    }
    __threadfence();
    grid.sync();

    // ---- Phase 2: BN1 scale/shift
    if (bid < 4) {
        int c = bid * 256 + tid;
        float s = 0.f, q = 0.f;
        for (int b = 0; b < B_; ++b) {
            s += psum[(size_t)b * C1 + c];
            q += psq[(size_t)b * C1 + c];
        }
        float m = s / n;
        float sc = g1[c] * rsqrtf(q / n - m * m + EPSF);
        sc1v[c] = sc;
        sh1v[c] = bb1[c] - m * sc;
    }
    __threadfence();
    grid.sync();

    // ---- Phase 3: fold1
    if (bid < 256) {
        float* rs = (float*)smem;
        int o = bid;
        int c = tid * 4;
        float4 w  = ((const float4*)(w1 + (size_t)o * C1))[tid];
        float4 sc = *(const float4*)(sc1v + c);
        float4 sh = *(const float4*)(sh1v + c);
        float p = w.x * sh.x + w.y * sh.y + w.z * sh.z + w.w * sh.w;
        uint2 pk;
        pk.x = (unsigned)f2bf(w.x * sc.x) | ((unsigned)f2bf(w.y * sc.y) << 16);
        pk.y = (unsigned)f2bf(w.z * sc.z) | ((unsigned)f2bf(w.w * sc.w) << 16);
        *((uint2*)(w1e + (size_t)o * C1 + c)) = pk;
        float pr = p;
        for (int m = 1; m < 64; m <<= 1) pr += __shfl_xor(pr, m);
        if (lane == 0) rs[wave] = pr;
        __syncthreads();
        if (tid == 0) b1e[o] = b1[o] + rs[0] + rs[1] + rs[2] + rs[3];
    }
    __threadfence();
    grid.sync();

    // ---- Phase 4: GEMM1 (R2 double-buffered body)
    {
        unsigned short* sA = (unsigned short*)smem;            // [2][256*32]
        unsigned short* sB = (unsigned short*)(smem + 32768);  // [2][128*BPITCH]
        int bn = bid & 15, b = bid >> 4;
        int wm = wave >> 1, wn = wave & 1;
        int l15 = lane & 15, q = lane >> 4;
        f32x4 acc[8][4] = {};
        int kk = tid >> 3, tc = tid & 7;
        const float* xbase = x + (size_t)b * C1 * T_ + (size_t)kk * T_ + (size_t)bn * 128 + tc * 4;

        auto stageA = [&](int buf, int k0) {
            #pragma unroll
            for (int i = 0; i < 4; ++i) {
                int idx = (wave * 4 + i) * 64 + lane;
                int row = idx >> 2, cq = idx & 3;
                g2l16(w1e + (size_t)row * C1 + k0 + cq * 8, sA + buf * 8192 + (wave * 4 + i) * 512);
            }
        };
        float4 rB[4];
        auto loadB = [&](int k0) {
            #pragma unroll
            for (int j = 0; j < 4; ++j)
                rB[j] = *(const float4*)(xbase + (size_t)k0 * T_ + j * 32);
        };
        auto writeB = [&](int buf) {
            #pragma unroll
            for (int j = 0; j < 4; ++j) {
                int t = tc * 4 + j * 32;
                unsigned short* p = sB + buf * 5120 + t * BPITCH + kk;
                p[0 * BPITCH] = f2bf(rB[j].x);
                p[1 * BPITCH] = f2bf(rB[j].y);
                p[2 * BPITCH] = f2bf(rB[j].z);
                p[3 * BPITCH] = f2bf(rB[j].w);
            }
        };

        loadB(0);
        stageA(0, 0);
        writeB(0);
        __syncthreads();
        int cur = 0;
        for (int kt = 0; kt < 32; ++kt) {
            int nxt = cur ^ 1;
            if (kt < 31) {
                loadB((kt + 1) * 32);
                stageA(nxt, (kt + 1) * 32);
            }
            bf16x8 bfr[4];
            #pragma unroll
            for (int ni = 0; ni < 4; ++ni)
                bfr[ni] = *((const bf16x8*)(sB + cur * 5120 + (wn * 64 + ni * 16 + l15) * BPITCH + q * 8));
            #pragma unroll
            for (int mi = 0; mi < 8; ++mi) {
                bf16x8 af = *((const bf16x8*)(sA + cur * 8192 + (wm * 128 + mi * 16 + l15) * 32 + q * 8));
                #pragma unroll
                for (int ni = 0; ni < 4; ++ni)
                    acc[mi][ni] = __builtin_amdgcn_mfma_f32_16x16x32_bf16(af, bfr[ni], acc[mi][ni], 0, 0, 0);
            }
            if (kt < 31) writeB(nxt);
            __syncthreads();
            cur = nxt;
        }
        int obase = wm * 128;
        int tbase = bn * 128 + wn * 64;
        int prow = (b * 16 + bn) * 2 + wn;
        #pragma unroll
        for (int mi = 0; mi < 8; ++mi) {
            int og = obase + mi * 16 + q * 4;
            float4 bias = *(const float4*)&b1e[og];
            float s0 = 0, s1 = 0, s2 = 0, s3 = 0, q0 = 0, q1 = 0, q2 = 0, q3 = 0;
            #pragma unroll
            for (int ni = 0; ni < 4; ++ni) {
                int t = tbase + ni * 16 + l15;
                float v0 = fmaxf(acc[mi][ni][0] + bias.x, 0.f);
                float v1 = fmaxf(acc[mi][ni][1] + bias.y, 0.f);
                float v2 = fmaxf(acc[mi][ni][2] + bias.z, 0.f);
                float v3 = fmaxf(acc[mi][ni][3] + bias.w, 0.f);
                s0 += v0; q0 += v0 * v0;  s1 += v1; q1 += v1 * v1;
                s2 += v2; q2 += v2 * v2;  s3 += v3; q3 += v3 * v3;
                uint2 pk;
                pk.x = (unsigned)f2bf(v0) | ((unsigned)f2bf(v1) << 16);
                pk.y = (unsigned)f2bf(v2) | ((unsigned)f2bf(v3) << 16);
                *(uint2*)&hT[((size_t)b * T_ + t) * C2 + og] = pk;
            }
            #pragma unroll
            for (int m = 1; m <= 8; m <<= 1) {
                s0 += __shfl_xor(s0, m); s1 += __shfl_xor(s1, m);
                s2 += __shfl_xor(s2, m); s3 += __shfl_xor(s3, m);
                q0 += __shfl_xor(q0, m); q1 += __shfl_xor(q1, m);
                q2 += __shfl_xor(q2, m); q3 += __shfl_xor(q3, m);
            }
            if (l15 == 0) {
                p2s[(size_t)(og + 0) * 1024 + prow] = s0;
                p2s[(size_t)(og + 1) * 1024 + prow] = s1;
                p2s[(size_t)(og + 2) * 1024 + prow] = s2;
                p2s[(size_t)(og + 3) * 1024 + prow] = s3;
                p2q[(size_t)(og + 0) * 1024 + prow] = q0;
                p2q[(size_t)(og + 1) * 1024 + prow] = q1;
                p2q[(size_t)(og + 2) * 1024 + prow] = q2;
                p2q[(size_t)(og + 3) * 1024 + prow] = q3;
            }
        }
    }
    __threadfence();
    grid.sync();

    // ---- Phase 5: BN2 scale/shift
    if (bid < 256) {
        float* rs = (float*)smem;
        float* rq = (float*)(smem + 16);
        int c = bid;
        float4 a  = *(const float4*)(p2s + (size_t)c * 1024 + tid * 4);
        float4 qv = *(const float4*)(p2q + (size_t)c * 1024 + tid * 4);
        float s = a.x + a.y + a.z + a.w;
        float q = qv.x + qv.y + qv.z + qv.w;
        for (int m = 1; m < 64; m <<= 1) { s += __shfl_xor(s, m); q += __shfl_xor(q, m); }
        if (lane == 0) { rs[wave] = s; rq[wave] = q; }
        __syncthreads();
        if (tid == 0) {
            s = rs[0] + rs[1] + rs[2] + rs[3];
            q = rq[0] + rq[1] + rq[2] + rq[3];
            float m0 = s / n;
            float sc = g2[c] * rsqrtf(q / n - m0 * m0 + EPSF);
            sc2v[c] = sc;
            sh2v[c] = bb2[c] - m0 * sc;
        }
    }
    __threadfence();
    grid.sync();

    // ---- Phase 6: fold2
    if (bid < 64) {
        float* rs = (float*)smem;
        int o = bid;
        float w = w2[(size_t)o * C2 + tid];
        w2e[(size_t)o * C2 + tid] = f2bf(w * sc2v[tid]);
        float p = w * sh2v[tid];
        for (int m = 1; m < 64; m <<= 1) p += __shfl_xor(p, m);
        if (lane == 0) rs[wave] = p;
        __syncthreads();
        if (tid == 0) b2e[o] = b2[o] + rs[0] + rs[1] + rs[2] + rs[3];
    }
    __threadfence();
    grid.sync();

    // ---- Phase 7: GEMM2
    {
        unsigned short* sA = (unsigned short*)smem;
        unsigned short* sB = (unsigned short*)(smem + 4096);
        int bn = bid & 15, b = bid >> 4;
        int l15 = lane & 15, q = lane >> 4;
        f32x4 acc[4][2] = {};
        const unsigned short* hblk = hT + ((size_t)b * T_ + (size_t)bn * 128) * C2;

        for (int k0 = 0; k0 < C2; k0 += 32) {
            {
                int idx = wave * 64 + lane;
                int row = idx >> 2, cq = idx & 3;
                g2l16(w2e + (size_t)row * C2 + k0 + cq * 8, sA + wave * 512);
            }
            #pragma unroll
            for (int i = 0; i < 2; ++i) {
                int idx = (wave * 2 + i) * 64 + lane;
                int row = idx >> 2, cq = idx & 3;
                g2l16(hblk + (size_t)row * C2 + k0 + cq * 8, sB + (wave * 2 + i) * 512);
            }
            __syncthreads();
            bf16x8 af[4], bfr[2];
            #pragma unroll
            for (int mi = 0; mi < 4; ++mi)
                af[mi] = *((const bf16x8*)(sA + (mi * 16 + l15) * 32 + q * 8));
            #pragma unroll
            for (int ni = 0; ni < 2; ++ni)
                bfr[ni] = *((const bf16x8*)(sB + (wave * 32 + ni * 16 + l15) * 32 + q * 8));
            #pragma unroll
            for (int mi = 0; mi < 4; ++mi)
                #pragma unroll
                for (int ni = 0; ni < 2; ++ni)
                    acc[mi][ni] = __builtin_amdgcn_mfma_f32_16x16x32_bf16(af[mi], bfr[ni], acc[mi][ni], 0, 0, 0);
            __syncthreads();
        }
        int tbase = bn * 128 + wave * 32;
        #pragma unroll
        for (int mi = 0; mi < 4; ++mi) {
            #pragma unroll
            for (int reg = 0; reg < 4; ++reg) {
                int o = mi * 16 + q * 4 + reg;
                float bias = b2e[o];
                size_t base = (o < 32)
                    ? ((size_t)b * 32 * T_ + (size_t)o * T_)
                    : (2097152u + (size_t)b * 32 * T_ + (size_t)(o - 32) * T_);
                #pragma unroll
                for (int ni = 0; ni < 2; ++ni) {
                    int t = tbase + ni * 16 + l15;
                    out[base + t] = acc[mi][ni][reg] + bias;
                }
            }
        }
    }
}

// ===================== Fallback: exact R2-proven 7-kernel chain =====================

__global__ __launch_bounds__(256) void k_stats(const float* __restrict__ x,
        float* __restrict__ psum, float* __restrict__ psq) {
    int ct = blockIdx.x, b = blockIdx.y, tid = threadIdx.x;
    int c0 = ct * 64;
    int cl = tid >> 2, t4 = tid & 3;
    const float* xrow = x + (size_t)b * C1 * T_ + (size_t)(c0 + cl) * T_ + t4 * 4;
    float s = 0.f, sq = 0.f;
    #pragma unroll 4
    for (int t0 = 0; t0 < T_; t0 += 16) {
        float4 v = *(const float4*)(xrow + t0);
        s  += v.x + v.y + v.z + v.w;
        sq += v.x * v.x + v.y * v.y + v.z * v.z + v.w * v.w;
    }
    s  += __shfl_xor(s, 1);  s  += __shfl_xor(s, 2);
    sq += __shfl_xor(sq, 1); sq += __shfl_xor(sq, 2);
    if (t4 == 0) {
        psum[(size_t)b * C1 + c0 + cl] = s;
        psq [(size_t)b * C1 + c0 + cl] = sq;
    }
}

__global__ __launch_bounds__(256) void k_bnstat1(const float* __restrict__ psum,
        const float* __restrict__ psq, const float* __restrict__ g1,
        const float* __restrict__ bb1, float* __restrict__ sc1, float* __restrict__ sh1) {
    int c = blockIdx.x * 256 + threadIdx.x;
    float s = 0.f, q = 0.f;
    for (int b = 0; b < B_; ++b) {
        s += psum[(size_t)b * C1 + c];
        q += psq[(size_t)b * C1 + c];
    }
    const float n = (float)(B_ * T_);
    float m = s / n;
    float sc = g1[c] * rsqrtf(q / n - m * m + EPSF);
    sc1[c] = sc;
    sh1[c] = bb1[c] - m * sc;
}

__global__ __launch_bounds__(256) void k_fold1(const float* __restrict__ w1,
        const float* __restrict__ b1, const float* __restrict__ sc1,
        const float* __restrict__ sh1, unsigned short* __restrict__ w1e,
        float* __restrict__ b1e) {
    int o = blockIdx.x, tid = threadIdx.x;
    int c = tid * 4;
    float4 w  = ((const float4*)(w1 + (size_t)o * C1))[tid];
    float4 sc = *(const float4*)(sc1 + c);
    float4 sh = *(const float4*)(sh1 + c);
    float p = w.x * sh.x + w.y * sh.y + w.z * sh.z + w.w * sh.w;
    uint2 pk;
    pk.x = (unsigned)f2bf(w.x * sc.x) | ((unsigned)f2bf(w.y * sc.y) << 16);
    pk.y = (unsigned)f2bf(w.z * sc.z) | ((unsigned)f2bf(w.w * sc.w) << 16);
    *((uint2*)(w1e + (size_t)o * C1 + c)) = pk;
    int wave = tid >> 6, lane = tid & 63;
    for (int m = 1; m < 64; m <<= 1) p += __shfl_xor(p, m);
    __shared__ float rs[4];
    if (lane == 0) rs[wave] = p;
    __syncthreads();
    if (tid == 0) b1e[o] = b1[o] + rs[0] + rs[1] + rs[2] + rs[3];
}

__global__ __launch_bounds__(256, 2) void k_gemm1(const float* __restrict__ x,
        const unsigned short* __restrict__ w1e, const float* __restrict__ b1e,
        unsigned short* __restrict__ hT, float* __restrict__ p2s, float* __restrict__ p2q) {
    __shared__ alignas(16) unsigned short sA[2][256 * 32];
    __shared__ alignas(16) unsigned short sB[2][128 * BPITCH];
    int bn = blockIdx.x, b = blockIdx.y;
    int tid = threadIdx.x;
    int wave = tid >> 6, lane = tid & 63;
    int wm = wave >> 1, wn = wave & 1;
    int l15 = lane & 15, q = lane >> 4;
    f32x4 acc[8][4] = {};
    int kk = tid >> 3, tc = tid & 7;
    const float* xbase = x + (size_t)b * C1 * T_ + (size_t)kk * T_ + (size_t)bn * 128 + tc * 4;

    auto stageA = [&](int buf, int k0) {
        #pragma unroll
        for (int i = 0; i < 4; ++i) {
            int idx = (wave * 4 + i) * 64 + lane;
            int row = idx >> 2, cq = idx & 3;
            g2l16(w1e + (size_t)row * C1 + k0 + cq * 8, &sA[buf][(wave * 4 + i) * 512]);
        }
    };
    float4 rB[4];
    auto loadB = [&](int k0) {
        #pragma unroll
        for (int j = 0; j < 4; ++j)
            rB[j] = *(const float4*)(xbase + (size_t)k0 * T_ + j * 32);
    };
    auto writeB = [&](int buf) {
        #pragma unroll
        for (int j = 0; j < 4; ++j) {
            int t = tc * 4 + j * 32;
            unsigned short* p = &sB[buf][t * BPITCH + kk];
            p[0 * BPITCH] = f2bf(rB[j].x);
            p[1 * BPITCH] = f2bf(rB[j].y);
            p[2 * BPITCH] = f2bf(rB[j].z);
            p[3 * BPITCH] = f2bf(rB[j].w);
        }
    };

    loadB(0);
    stageA(0, 0);
    writeB(0);
    __syncthreads();
    int cur = 0;
    for (int kt = 0; kt < 32; ++kt) {
        int nxt = cur ^ 1;
        if (kt < 31) {
            loadB((kt + 1) * 32);
            stageA(nxt, (kt + 1) * 32);
        }
        bf16x8 bfr[4];
        #pragma unroll
        for (int ni = 0; ni < 4; ++ni)
            bfr[ni] = *((const bf16x8*)&sB[cur][(wn * 64 + ni * 16 + l15) * BPITCH + q * 8]);
        #pragma unroll
        for (int mi = 0; mi < 8; ++mi) {
            bf16x8 af = *((const bf16x8*)&sA[cur][(wm * 128 + mi * 16 + l15) * 32 + q * 8]);
            #pragma unroll
            for (int ni = 0; ni < 4; ++ni)
                acc[mi][ni] = __builtin_amdgcn_mfma_f32_16x16x32_bf16(af, bfr[ni], acc[mi][ni], 0, 0, 0);
        }
        if (kt < 31) writeB(nxt);
        __syncthreads();
        cur = nxt;
    }
    int obase = wm * 128;
    int tbase = bn * 128 + wn * 64;
    int prow = (b * 16 + bn) * 2 + wn;
    #pragma unroll
    for (int mi = 0; mi < 8; ++mi) {
        int og = obase + mi * 16 + q * 4;
        float4 bias = *(const float4*)&b1e[og];
        float s0 = 0, s1 = 0, s2 = 0, s3 = 0, q0 = 0, q1 = 0, q2 = 0, q3 = 0;
        #pragma unroll
        for (int ni = 0; ni < 4; ++ni) {
            int t = tbase + ni * 16 + l15;
            float v0 = fmaxf(acc[mi][ni][0] + bias.x, 0.f);
            float v1 = fmaxf(acc[mi][ni][1] + bias.y, 0.f);
            float v2 = fmaxf(acc[mi][ni][2] + bias.z, 0.f);
            float v3 = fmaxf(acc[mi][ni][3] + bias.w, 0.f);
            s0 += v0; q0 += v0 * v0;  s1 += v1; q1 += v1 * v1;
            s2 += v2; q2 += v2 * v2;  s3 += v3; q3 += v3 * v3;
            uint2 pk;
            pk.x = (unsigned)f2bf(v0) | ((unsigned)f2bf(v1) << 16);
            pk.y = (unsigned)f2bf(v2) | ((unsigned)f2bf(v3) << 16);
            *(uint2*)&hT[((size_t)b * T_ + t) * C2 + og] = pk;
        }
        #pragma unroll
        for (int m = 1; m <= 8; m <<= 1) {
            s0 += __shfl_xor(s0, m); s1 += __shfl_xor(s1, m);
            s2 += __shfl_xor(s2, m); s3 += __shfl_xor(s3, m);
            q0 += __shfl_xor(q0, m); q1 += __shfl_xor(q1, m);
            q2 += __shfl_xor(q2, m); q3 += __shfl_xor(q3, m);
        }
        if (l15 == 0) {
            p2s[(size_t)(og + 0) * 1024 + prow] = s0;
            p2s[(size_t)(og + 1) * 1024 + prow] = s1;
            p2s[(size_t)(og + 2) * 1024 + prow] = s2;
            p2s[(size_t)(og + 3) * 1024 + prow] = s3;
            p2q[(size_t)(og + 0) * 1024 + prow] = q0;
            p2q[(size_t)(og + 1) * 1024 + prow] = q1;
            p2q[(size_t)(og + 2) * 1024 + prow] = q2;
            p2q[(size_t)(og + 3) * 1024 + prow] = q3;
        }
    }
}

__global__ __launch_bounds__(256) void k_bnstat2(const float* __restrict__ p2s,
        const float* __restrict__ p2q, const float* __restrict__ g2,
        const float* __restrict__ bb2, float* __restrict__ sc2, float* __restrict__ sh2) {
    int c = blockIdx.x, tid = threadIdx.x;
    float4 a  = *(const float4*)(p2s + (size_t)c * 1024 + tid * 4);
    float4 qv = *(const float4*)(p2q + (size_t)c * 1024 + tid * 4);
    float s = a.x + a.y + a.z + a.w;
    float q = qv.x + qv.y + qv.z + qv.w;
    for (int m = 1; m < 64; m <<= 1) { s += __shfl_xor(s, m); q += __shfl_xor(q, m); }
    __shared__ float rs[4], rq[4];
    int wave = tid >> 6, lane = tid & 63;
    if (lane == 0) { rs[wave] = s; rq[wave] = q; }
    __syncthreads();
    if (tid == 0) {
        s = rs[0] + rs[1] + rs[2] + rs[3];
        q = rq[0] + rq[1] + rq[2] + rq[3];
        const float n = (float)(B_ * T_);
        float m0 = s / n;
        float sc = g2[c] * rsqrtf(q / n - m0 * m0 + EPSF);
        sc2[c] = sc;
        sh2[c] = bb2[c] - m0 * sc;
    }
}

__global__ __launch_bounds__(256) void k_fold2(const float* __restrict__ w2,
        const float* __restrict__ b2, const float* __restrict__ sc2,
        const float* __restrict__ sh2, unsigned short* __restrict__ w2e,
        float* __restrict__ b2e) {
    int o = blockIdx.x, tid = threadIdx.x;
    float w = w2[(size_t)o * C2 + tid];
    w2e[(size_t)o * C2 + tid] = f2bf(w * sc2[tid]);
    float p = w * sh2[tid];
    int wave = tid >> 6, lane = tid & 63;
    for (int m = 1; m < 64; m <<= 1) p += __shfl_xor(p, m);
    __shared__ float rs[4];
    if (lane == 0) rs[wave] = p;
    __syncthreads();
    if (tid == 0) b2e[o] = b2[o] + rs[0] + rs[1] + rs[2] + rs[3];
}

__global__ __launch_bounds__(256) void k_gemm2(const unsigned short* __restrict__ hT,
        const unsigned short* __restrict__ w2e, const float* __restrict__ b2e,
        float* __restrict__ out) {
    __shared__ alignas(16) unsigned short sA[64 * 32];
    __shared__ alignas(16) unsigned short sB[128 * 32];
    int bn = blockIdx.x, b = blockIdx.y;
    int tid = threadIdx.x;
    int wave = tid >> 6, lane = tid & 63;
    int l15 = lane & 15, q = lane >> 4;
    f32x4 acc[4][2] = {};
    const unsigned short* hblk = hT + ((size_t)b * T_ + (size_t)bn * 128) * C2;

    for (int k0 = 0; k0 < C2; k0 += 32) {
        {
            int idx = wave * 64 + lane;
            int row = idx >> 2, cq = idx & 3;
            g2l16(w2e + (size_t)row * C2 + k0 + cq * 8, sA + wave * 512);
        }
        #pragma unroll
        for (int i = 0; i < 2; ++i) {
            int idx = (wave * 2 + i) * 64 + lane;
            int row = idx >> 2, cq = idx & 3;
            g2l16(hblk + (size_t)row * C2 + k0 + cq * 8, sB + (wave * 2 + i) * 512);
        }
        __syncthreads();
        bf16x8 af[4], bfr[2];
        #pragma unroll
        for (int mi = 0; mi < 4; ++mi)
            af[mi] = *((const bf16x8*)(sA + (mi * 16 + l15) * 32 + q * 8));
        #pragma unroll
        for (int ni = 0; ni < 2; ++ni)
            bfr[ni] = *((const bf16x8*)(sB + (wave * 32 + ni * 16 + l15) * 32 + q * 8));
        #pragma unroll
        for (int mi = 0; mi < 4; ++mi)
            #pragma unroll
            for (int ni = 0; ni < 2; ++ni)
                acc[mi][ni] = __builtin_amdgcn_mfma_f32_16x16x32_bf16(af[mi], bfr[ni], acc[mi][ni], 0, 0, 0);
        __syncthreads();
    }
    int tbase = bn * 128 + wave * 32;
    #pragma unroll
    for (int mi = 0; mi < 4; ++mi) {
        #pragma unroll
        for (int reg = 0; reg < 4; ++reg) {
            int o = mi * 16 + q * 4 + reg;
            float bias = b2e[o];
            size_t base = (o < 32)
                ? ((size_t)b * 32 * T_ + (size_t)o * T_)
                : (2097152u + (size_t)b * 32 * T_ + (size_t)(o - 32) * T_);
            #pragma unroll
            for (int ni = 0; ni < 2; ++ni) {
                int t = tbase + ni * 16 + l15;
                out[base + t] = acc[mi][ni][reg] + bias;
            }
        }
    }
}

extern "C" void kernel_launch(void* const* d_in, const int* in_sizes, int n_in,
                              void* d_out, int out_size, void* d_ws, size_t ws_size,
                              hipStream_t stream) {
    const float* x   = (const float*)d_in[0];
    const float* g1  = (const float*)d_in[1];
    const float* bb1 = (const float*)d_in[2];
    const float* w1  = (const float*)d_in[3];
    const float* b1  = (const float*)d_in[4];
    const float* g2  = (const float*)d_in[5];
    const float* bb2 = (const float*)d_in[6];
    const float* w2  = (const float*)d_in[7];
    const float* b2  = (const float*)d_in[8];
    float* out = (float*)d_out;

    char* ws = (char*)d_ws;
    float* b1e  = (float*)(ws + 0);
    float* b2e  = (float*)(ws + 4096);
    float* psum = (float*)(ws + 8192);
    float* psq  = (float*)(ws + 139264);
    float* p2s  = (float*)(ws + 270336);
    float* p2q  = (float*)(ws + 1318912);
    unsigned short* w1e = (unsigned short*)(ws + 2367488);
    unsigned short* w2e = (unsigned short*)(ws + 2891776);
    float* sc1 = (float*)(ws + 2924544);
    float* sh1 = (float*)(ws + 2928640);
    float* sc2 = (float*)(ws + 2932736);
    float* sh2 = (float*)(ws + 2933760);
    unsigned short* hT  = (unsigned short*)(ws + 2934784);

    // Gate 1: co-residency check (stream-free host query; capture-safe).
    int maxBlk = 0;
    hipError_t qe = hipOccupancyMaxActiveBlocksPerMultiprocessor(
        &maxBlk, (const void*)k_mega, 256, 0);
    if (qe == hipSuccess && maxBlk >= 2) {
        void* args[] = { (void*)&x, (void*)&g1, (void*)&bb1, (void*)&w1, (void*)&b1,
                         (void*)&g2, (void*)&bb2, (void*)&w2, (void*)&b2, (void*)&out,
                         (void*)&psum, (void*)&psq, (void*)&p2s, (void*)&p2q,
                         (void*)&w1e, (void*)&w2e, (void*)&b1e, (void*)&b2e,
                         (void*)&sc1, (void*)&sh1, (void*)&sc2, (void*)&sh2, (void*)&hT };
        hipError_t le = hipLaunchCooperativeKernel((void*)k_mega, dim3(512), dim3(256),
                                                   args, 0, stream);
        if (le == hipSuccess) return;           // Gate 2: launch accepted
    }

    // Fallback: exact R2-proven chain.
    k_stats  <<<dim3(16, 32), dim3(256), 0, stream>>>(x, psum, psq);
    k_bnstat1<<<dim3(4),      dim3(256), 0, stream>>>(psum, psq, g1, bb1, sc1, sh1);
    k_fold1  <<<dim3(256),    dim3(256), 0, stream>>>(w1, b1, sc1, sh1, w1e, b1e);
    k_gemm1  <<<dim3(16, 32), dim3(256), 0, stream>>>(x, w1e, b1e, hT, p2s, p2q);
    k_bnstat2<<<dim3(256),    dim3(256), 0, stream>>>(p2s, p2q, g2, bb2, sc2, sh2);
    k_fold2  <<<dim3(64),     dim3(256), 0, stream>>>(w2, b2, sc2, sh2, w2e, b2e);
    k_gemm2  <<<dim3(16, 32), dim3(256), 0, stream>>>(hT, w2e, b2e, out);
}